// Round 3
// baseline (260.102 us; speedup 1.0000x reference)
//
#include <hip/hip_runtime.h>
#include <stdint.h>

// B=4, DIM=256, W0=H0=128, HEADS=8, HEAD_DIM=32, FOLD=2, PROP=4
// 128 folded tiles (bb), each c=32, 64x64 (N=4096), M=16 centers.
// split_mask==0 => 7x7 conv contributes nothing; Wv/bv dead. All I/O f32.
// Pipeline: k0 geo-centers | k1a x-centers | k1b MFMA sim+rowsum+dnum+Gram partials
//           | k1c reduce + analytic GN stats | k2 GN-fold + W*alpha f16
//           | kf_proj: regenerate pre (sim.denss MFMA) in LDS + proj MFMA + SiLU
// Round-3: g_preout (32MB write + 32MB read) eliminated. GN stats computed
// analytically: s1 = sum_m rsum[m]*rowsum_c(denss), s2 = sum_{mm'} G[mm']*P[mm'],
// G = sim^T sim via 2 free extra MFMAs in k1b (reuses dnum A-frag as both operands).

typedef __attribute__((ext_vector_type(8))) short short8;
typedef __attribute__((ext_vector_type(4))) float floatx4;
typedef __fp16 fp16x2 __attribute__((ext_vector_type(2)));

#define SIMW 264     // padded half stride for [16][px] LDS tiles (528 B, 2-way banks)

__device__ float g_sbp[256];                           // per-tile GN partials [bb][2]
__device__ float g_bias[1024];
__device__ __attribute__((aligned(16))) _Float16 g_Wa[4*256*256];   // W*alpha, f16 [b][o][c]
__device__ float g_cenraw[128*16*32];
__device__ float g_cenhat[128*16*32];
__device__ float g_gcenhat[16*16*4];
__device__ __attribute__((aligned(16))) _Float16 g_sim[(size_t)128*4096*16];   // [tile][n][m]
__device__ float g_dnum[128*16*16*32];                 // [tile][chunk][m][c]
__device__ float g_Gp[(size_t)128*16*256];             // [tile][chunk][m][m'] Gram partials
__device__ float g_rsum[128*16*16];
__device__ __attribute__((aligned(16))) unsigned g_dnh2[128*256];   // denss f16 [tile][c][mpair]

static __device__ __forceinline__ fp16x2 as_h2(unsigned u) { return __builtin_bit_cast(fp16x2, u); }
static __device__ __forceinline__ unsigned pk(float a, float b) {
  return __builtin_bit_cast(unsigned, __builtin_amdgcn_cvt_pkrtz(a, b));
}
static __device__ __forceinline__ float h16(float v) {   // f32 -> f16(RTZ, matches pk) -> f32
  return (float)as_h2(pk(v, 0.f))[0];
}
#if __has_builtin(__builtin_amdgcn_fdot2)
static __device__ __forceinline__ float fdot2(fp16x2 a, fp16x2 b, float c) {
  return __builtin_amdgcn_fdot2(a, b, c, false);
}
#else
static __device__ __forceinline__ float fdot2(fp16x2 a, fp16x2 b, float c) {
  return c + (float)a[0]*(float)b[0] + (float)a[1]*(float)b[1];
}
#endif
static __device__ __forceinline__ float sum16(const float* p) {
  const float4* q = (const float4*)p;
  float4 a = q[0], b = q[1], c = q[2], d = q[3];
  return (a.x+a.y+a.z+a.w) + (b.x+b.y+b.z+b.w) + (c.x+c.y+c.z+c.w) + (d.x+d.y+d.z+d.w);
}
static __device__ __forceinline__ float sigm(float z) {
  return __builtin_amdgcn_rcpf(1.f + __expf(-z));
}

// ---------------- k0: geo pooled centers ----------------
__global__ __launch_bounds__(64) void k0_geo(const float* __restrict__ xyz) {
  __shared__ float gc[64];
  const int gti = blockIdx.x;
  const int bg = gti >> 2, f1 = (gti >> 1) & 1, f2 = gti & 1;
  const int t = threadIdx.x;
  if (t < 48) {
    const int m = t / 3, ch = t - 3*(t/3);
    const int pi = m >> 2, pj = m & 3;
    const float* p = xyz + (size_t)(bg*3+ch)*16384 + (f1*64 + pi*16)*128 + f2*64 + pj*16;
    float s = 0.f;
    #pragma unroll
    for (int r = 0; r < 16; ++r) s += sum16(p + r*128);
    gc[m*4+ch] = s * (1.f/256.f);
  }
  __syncthreads();
  if (t < 16) {
    float g0 = gc[t*4], g1 = gc[t*4+1], g2 = gc[t*4+2];
    float inv = 1.f / fmaxf(sqrtf(g0*g0+g1*g1+g2*g2), 1e-12f);
    float* o = g_gcenhat + gti*64 + t*4;
    o[0] = g0*inv; o[1] = g1*inv; o[2] = g2*inv; o[3] = 0.f;
  }
}

// ---------------- k1a: x pooled centers + normalize ----------------
__global__ __launch_bounds__(128) void k1a_cen(const float* __restrict__ x) {
  __shared__ float cenL[128];
  __shared__ float invL[4];
  const int blk = blockIdx.x;
  const int bb = blk >> 2, pi = blk & 3;
  const int b = bb >> 5, e = (bb >> 2) & 7, f1 = (bb >> 1) & 1, f2 = bb & 1;
  const int tid = threadIdx.x;
  const int c = tid >> 2, pj = tid & 3;
  const int m = pi*4 + pj;
  const float* p = x + ((size_t)(b*256 + e*32 + c)*128 + f1*64 + pi*16)*128 + f2*64 + pj*16;
  float s = 0.f;
  #pragma unroll
  for (int r = 0; r < 16; ++r) s += sum16(p + r*128);
  const float raw = s * (1.f/256.f);
  cenL[pj*32 + c] = raw;
  g_cenraw[(bb*16 + m)*32 + c] = raw;
  __syncthreads();
  if (tid < 4) {
    float ss = 0.f;
    #pragma unroll
    for (int cc = 0; cc < 32; ++cc) { float v = cenL[tid*32+cc]; ss += v*v; }
    invL[tid] = 1.f / fmaxf(sqrtf(ss), 1e-12f);
  }
  __syncthreads();
  g_cenhat[(bb*16 + m)*32 + c] = raw * invL[pj];
}

// ---------------- k1b: MFMA sim + rowsum + dnum + Gram partials ----------------
// 2048 blocks (tile x 16 chunks of 256 px), 256 threads = 4 waves.
__global__ __launch_bounds__(256, 4) void k1b_sim(const float* __restrict__ x,
                                                  const float* __restrict__ xyz,
                                                  const float* __restrict__ salpha,
                                                  const float* __restrict__ sbeta) {
  __shared__ __attribute__((aligned(16))) unsigned  xL[256*20];    // 20 KB
  __shared__ __attribute__((aligned(16))) _Float16 simS[16*SIMW];  // 8.25 KB
  __shared__ __attribute__((aligned(16))) _Float16 gT[16*SIMW];    // 8.25 KB gg^2 -> GL overlay
  __shared__ __attribute__((aligned(16))) unsigned chP[16*16];
  __shared__ float gcenL[64];
  __shared__ float rsW[4*16];
  __shared__ float dnumL[512];
  float* GL = (float*)gT;              // 256 f32 Gram accumulator (gT dead after phase 2)
  const int blk = blockIdx.x;
  const int bb = blk >> 4, ck = blk & 15;
  const int b = bb >> 5, e = (bb >> 2) & 7, f1 = (bb >> 1) & 1, f2 = bb & 1;
  const int gti = ((e & 3) << 2) | (f1 << 1) | f2;
  const int tid = threadIdx.x, lane = tid & 63, wave = tid >> 6;
  const int lm = lane & 15, quad = lane >> 4;
  const float alpha = salpha[0], beta = sbeta[0];
  const float* xt = x + (((size_t)(b*256 + e*32))*128 + f1*64)*128 + f2*64;

  {
    const float2 cp = *(const float2*)(g_cenhat + bb*512 + tid*2);
    chP[tid] = pk(cp.x, cp.y);
  }
  if (tid < 64) gcenL[tid] = g_gcenhat[gti*64 + tid];
  dnumL[tid] = 0.f; dnumL[tid + 256] = 0.f;
  __syncthreads();

  // ---- phase 1: load own pixel, pack f16 -> xL, invn, geo gg^2 -> gT ----
  const int ng = ck*256 + tid;
  const int wi = ng >> 6, hi = ng & 63;
  const int addr = wi*128 + hi;
  {
    float ss = 0.f;
    unsigned xp[16];
    #pragma unroll
    for (int p = 0; p < 16; ++p) {
      const float v0 = xt[(size_t)(2*p)*16384 + addr];
      const float v1 = xt[(size_t)(2*p+1)*16384 + addr];
      ss += v0*v0 + v1*v1;
      xp[p] = pk(v0, v1);
    }
    uint4 u0 = {xp[0],xp[1],xp[2],xp[3]};
    uint4 u1 = {xp[4],xp[5],xp[6],xp[7]};
    uint4 u2 = {xp[8],xp[9],xp[10],xp[11]};
    uint4 u3 = {xp[12],xp[13],xp[14],xp[15]};
    *(uint4*)(xL + tid*20)      = u0;
    *(uint4*)(xL + tid*20 + 4)  = u1;
    *(uint4*)(xL + tid*20 + 8)  = u2;
    *(uint4*)(xL + tid*20 + 12) = u3;
    const float invn = __builtin_amdgcn_rcpf(fmaxf(sqrtf(ss), 1e-12f));
    ((float*)xL)[tid*20 + 16] = invn;
  }
  {
    const float* gp = xyz + (size_t)((e & 3)*3)*16384 + (f1*64 + wi)*128 + f2*64 + hi;
    float g0 = gp[0], g1 = gp[16384], g2 = gp[32768];
    const float invg = __builtin_amdgcn_rcpf(fmaxf(sqrtf(g0*g0+g1*g1+g2*g2), 1e-12f));
    g0 *= invg; g1 *= invg; g2 *= invg;
    #pragma unroll
    for (int m = 0; m < 16; ++m) {
      const float* gh = gcenL + m*4;
      const float dg = gh[0]*g0 + gh[1]*g1 + gh[2]*g2;
      const float gg = sigm(beta + alpha*dg);
      gT[m*SIMW + tid] = (_Float16)(gg*gg);
    }
  }
  __syncthreads();

  // ---- phase 2: sim via MFMA (A=cen_hat[m][c], B=x_f16[px][c], K=32) ----
  {
    const short8 afx = *(const short8*)((const _Float16*)chP + lm*32 + quad*8);
    float rsacc[4] = {0.f, 0.f, 0.f, 0.f};
    #pragma unroll
    for (int t = 0; t < 4; ++t) {
      const int px = wave*64 + t*16 + lm;
      const short8 bfx = *(const short8*)((const _Float16*)xL + px*40 + quad*8);
      floatx4 d = {0.f,0.f,0.f,0.f};
      d = __builtin_amdgcn_mfma_f32_16x16x32_f16(afx, bfx, d, 0, 0, 0);
      const float invn = ((const float*)xL)[px*20 + 16];
      #pragma unroll
      for (int r = 0; r < 4; ++r) {
        const int m = quad*4 + r;
        const float gg2 = (float)gT[m*SIMW + px];
        const float sv = sigm(beta + alpha * d[r] * invn) * gg2;
        rsacc[r] += sv;
        simS[m*SIMW + px] = (_Float16)sv;
      }
    }
    #pragma unroll
    for (int r = 0; r < 4; ++r) {
      float v = rsacc[r];
      v += __shfl_xor(v, 1, 64); v += __shfl_xor(v, 2, 64);
      v += __shfl_xor(v, 4, 64); v += __shfl_xor(v, 8, 64);
      if (lm == 0) rsW[wave*16 + quad*4 + r] = v;
    }
  }
  __syncthreads();
  if (tid < 256) GL[tid] = 0.f;        // gT region dead; becomes Gram accumulator
  __syncthreads();

  // ---- phase 3a: export sim f16 [px][m] to global ----
  {
    unsigned w[8];
    const unsigned short* sp = (const unsigned short*)simS;
    #pragma unroll
    for (int p = 0; p < 8; ++p)
      w[p] = (unsigned)sp[(2*p)*SIMW + tid] | ((unsigned)sp[(2*p+1)*SIMW + tid] << 16);
    _Float16* gp = g_sim + ((size_t)bb*4096 + ng)*16;
    *(uint4*)gp       = *(const uint4*)&w[0];
    *(uint4*)(gp + 8) = *(const uint4*)&w[4];
  }
  if (tid < 16)
    g_rsum[(bb*16 + ck)*16 + tid] = rsW[tid] + rsW[16+tid] + rsW[32+tid] + rsW[48+tid];

  // ---- phase 3b: dnum[m][c] partials + Gram partials via MFMA ----
  {
    floatx4 acc0 = {0.f,0.f,0.f,0.f}, acc1 = {0.f,0.f,0.f,0.f};
    floatx4 accG = {0.f,0.f,0.f,0.f};
    #pragma unroll
    for (int ks = 0; ks < 2; ++ks) {
      const int kb = wave*64 + ks*32 + quad*8;                  // local px base
      const short8 af = *(const short8*)(simS + lm*SIMW + kb);  // A[m=lm][k=px]; also B[k=px][j=m'=lm]
      const int ag = ck*512 + ((kb >> 6)*128) + (kb & 63);
      const float* pb0 = xt + (size_t)lm*16384 + ag;            // B[c=lm][k=px]
      const float* pb1 = pb0 + (size_t)16*16384;                // c = lm+16
      short8 bf0, bf1;
      #pragma unroll
      for (int t = 0; t < 8; ++t) bf0[t] = __builtin_bit_cast(short, (_Float16)pb0[t]);
      #pragma unroll
      for (int t = 0; t < 8; ++t) bf1[t] = __builtin_bit_cast(short, (_Float16)pb1[t]);
      acc0 = __builtin_amdgcn_mfma_f32_16x16x32_f16(af, bf0, acc0, 0, 0, 0);
      acc1 = __builtin_amdgcn_mfma_f32_16x16x32_f16(af, bf1, acc1, 0, 0, 0);
      accG = __builtin_amdgcn_mfma_f32_16x16x32_f16(af, af,  accG, 0, 0, 0);
    }
    #pragma unroll
    for (int r = 0; r < 4; ++r) {
      atomicAdd(&dnumL[(quad*4 + r)*32 + lm],      acc0[r]);
      atomicAdd(&dnumL[(quad*4 + r)*32 + 16 + lm], acc1[r]);
      atomicAdd(&GL[(quad*4 + r)*16 + lm],         accG[r]);
    }
  }
  __syncthreads();
  g_dnum[(size_t)(bb*16 + ck)*512 + tid]       = dnumL[tid];
  g_dnum[(size_t)(bb*16 + ck)*512 + 256 + tid] = dnumL[tid + 256];
  g_Gp[(size_t)(bb*16 + ck)*256 + tid]         = GL[tid];
}

// ---------------- k1c: reduce partials -> denss f16 + analytic GN stats ----------------
__global__ __launch_bounds__(512) void k1c_red() {
  __shared__ float denssL[512];
  __shared__ float rsL[16];
  __shared__ float red[16];
  const int bb = blockIdx.x, tid = threadIdx.x, lane = tid & 63, wv = tid >> 6;
  if (tid < 16) {
    float r = 1.f;
    #pragma unroll
    for (int k = 0; k < 16; ++k) r += g_rsum[(bb*16 + k)*16 + tid];
    rsL[tid] = r;
  }
  float a = g_cenraw[bb*512 + tid];
  #pragma unroll
  for (int k = 0; k < 16; ++k) a += g_dnum[(size_t)bb*8192 + k*512 + tid];
  __syncthreads();
  denssL[tid] = a / rsL[tid >> 5];       // tid = m*32 + c
  __syncthreads();
  if (tid < 256) {
    const int c = tid >> 3, mp = tid & 7;
    g_dnh2[bb*256 + c*8 + mp] = pk(denssL[(2*mp)*32 + c], denssL[(2*mp+1)*32 + c]);
  }
  // ---- GN stats: s1 = sum_m rs[m]*sum_c d16; s2 = sum_{mm'} G[mm']*P[mm'] ----
  float contrib = 0.f;
  if (tid < 256) {
    const int m = tid >> 4, m2 = tid & 15;
    float g = 0.f;
    #pragma unroll
    for (int k = 0; k < 16; ++k) g += g_Gp[((size_t)bb*16 + k)*256 + tid];
    float p = 0.f;
    #pragma unroll
    for (int c = 0; c < 32; ++c)
      p += h16(denssL[m*32 + c]) * h16(denssL[m2*32 + c]);
    contrib = g * p;
  }
  float s1t = 0.f;
  if (tid < 16) {
    float sc = 0.f;
    #pragma unroll
    for (int c = 0; c < 32; ++c) sc += h16(denssL[tid*32 + c]);
    s1t = (rsL[tid] - 1.f) * sc;
  }
  #pragma unroll
  for (int off = 1; off < 64; off <<= 1) {
    contrib += __shfl_xor(contrib, off, 64);
    s1t     += __shfl_xor(s1t, off, 64);
  }
  if (lane == 0) { red[wv] = contrib; red[8 + wv] = s1t; }
  __syncthreads();
  if (tid == 0) {
    float s2 = 0.f, s1 = 0.f;
    #pragma unroll
    for (int w = 0; w < 8; ++w) { s2 += red[w]; s1 += red[8 + w]; }
    g_sbp[bb*2]     = s1;
    g_sbp[bb*2 + 1] = s2;
  }
}

// ---------------- k2: GN fold + bias + W*alpha (f16) ----------------
__global__ __launch_bounds__(256) void k2_prep(const float* __restrict__ Wp,
                                               const float* __restrict__ bpr,
                                               const float* __restrict__ gnw,
                                               const float* __restrict__ gnb) {
  __shared__ float betaL[256];
  __shared__ float alphaL[256];
  __shared__ float S12[2];
  const int b = blockIdx.x, t = threadIdx.x;
  if (t < 64) {
    float v1 = 0.f, v2 = 0.f;
    if (t < 32) { v1 = g_sbp[(b*32 + t)*2]; v2 = g_sbp[(b*32 + t)*2 + 1]; }
    #pragma unroll
    for (int off = 1; off < 64; off <<= 1) { v1 += __shfl_xor(v1, off, 64); v2 += __shfl_xor(v2, off, 64); }
    if (t == 0) { S12[0] = v1; S12[1] = v2; }
  }
  __syncthreads();
  const float S1 = S12[0];
  const float S2 = S12[1];
  const float inv_n = 1.f / 4194304.f;
  const float mu  = S1 * inv_n;
  const float inv = rsqrtf(fmaxf(S2*inv_n - mu*mu, 0.f) + 1e-5f);
  const float a = inv * gnw[t];
  alphaL[t] = a;
  betaL[t] = gnb[t] - mu * a;
  __syncthreads();
  float k = bpr[t];
  const float* wr = Wp + t*256;
  _Float16* wa = g_Wa + ((size_t)b*256 + t)*256;
  for (int c = 0; c < 256; c += 8) {
    const float4 w0 = *(const float4*)(wr + c);
    const float4 w1 = *(const float4*)(wr + c + 4);
    k += w0.x*betaL[c+0] + w0.y*betaL[c+1] + w0.z*betaL[c+2] + w0.w*betaL[c+3]
       + w1.x*betaL[c+4] + w1.y*betaL[c+5] + w1.z*betaL[c+6] + w1.w*betaL[c+7];
    uint4 o;
    o.x = pk(w0.x*alphaL[c+0], w0.y*alphaL[c+1]);
    o.y = pk(w0.z*alphaL[c+2], w0.w*alphaL[c+3]);
    o.z = pk(w1.x*alphaL[c+4], w1.y*alphaL[c+5]);
    o.w = pk(w1.z*alphaL[c+6], w1.w*alphaL[c+7]);
    *(uint4*)(wa + c) = o;
  }
  g_bias[b*256 + t] = k;
}

// ---------------- kf_proj: regenerate pre in LDS (sim.denss MFMA) + proj + SiLU --------
// Grid/threads identical to old k3 (1024 x 256). Phase A: wave w computes heads
// 2w,2w+1 -> pre[64px][256c] f16 in XOR-swizzled LDS. Phase B: old k3 with B-frags
// from LDS. Eliminates g_preout (64MB HBM round-trip).
__global__ __launch_bounds__(256, 4) void kf_proj(float* __restrict__ out) {
  __shared__ __attribute__((aligned(16))) _Float16 preL[64*256];  // 32 KB, swizzled
  __shared__ float biasL[256];
  const int blk = blockIdx.x;
  const int b = blk >> 8, pb = blk & 255;
  const int f1 = pb >> 7, f2 = pb & 1;
  const int nbase = ((pb >> 1) & 63) * 64;
  const int tid = threadIdx.x, lane = tid & 63, wave = tid >> 6;
  const int lm = lane & 15, quad = lane >> 4;
  const int m0 = wave*64;
  biasL[tid] = g_bias[b*256 + tid];

  // ---- phase A: pre[px][c] = sum_m sim[px][m]*denss[m][c], K=16 (zero-padded to 32)
  #pragma unroll
  for (int eh = 0; eh < 2; ++eh) {
    const int e = wave*2 + eh;
    const int bb = b*32 + e*4 + f1*2 + f2;
    short8 bf0 = {}, bf1 = {};
    if (quad < 2) {                    // k = quad*8+t in [0,16): real m; quads 2,3 zero
      const _Float16* dp = (const _Float16*)g_dnh2 + (size_t)bb*512 + quad*8;
      bf0 = *(const short8*)(dp + lm*16);          // B[k=m][j=c=lm]
      bf1 = *(const short8*)(dp + (16 + lm)*16);   // c = 16+lm
    }
    #pragma unroll
    for (int pt = 0; pt < 4; ++pt) {
      const short8 af = *(const short8*)(g_sim
          + ((size_t)bb*4096 + nbase + pt*16 + lm)*16 + (quad & 1)*8);  // A[i=px=lm][k=m]
      floatx4 c0 = {0.f,0.f,0.f,0.f}, c1 = {0.f,0.f,0.f,0.f};
      c0 = __builtin_amdgcn_mfma_f32_16x16x32_f16(af, bf0, c0, 0, 0, 0);
      c1 = __builtin_amdgcn_mfma_f32_16x16x32_f16(af, bf1, c1, 0, 0, 0);
      #pragma unroll
      for (int r = 0; r < 4; ++r) {
        const int px = pt*16 + quad*4 + r;
        const int swz = (px & 7) << 4;
        const int b0 = (px*512 + (e*32 + lm)*2) ^ swz;
        const int b1 = (px*512 + (e*32 + 16 + lm)*2) ^ swz;
        *(_Float16*)((char*)preL + b0) = (_Float16)c0[r];
        *(_Float16*)((char*)preL + b1) = (_Float16)c1[r];
      }
    }
  }
  __syncthreads();

  // ---- phase B: proj MFMA + SiLU (old k3, B-frags from swizzled LDS) ----
  floatx4 acc[4][4] = {};
  #pragma unroll
  for (int ks = 0; ks < 8; ++ks) {
    const _Float16* abase = g_Wa + ((size_t)b*256)*256 + (size_t)ks*32 + quad*8;
    short8 afr[4], bfr[4];
    #pragma unroll
    for (int mi = 0; mi < 4; ++mi)
      afr[mi] = *(const short8*)(abase + (size_t)(m0 + mi*16 + lm)*256);
    #pragma unroll
    for (int ni = 0; ni < 4; ++ni) {
      const int row = ni*16 + lm;
      const int byte = (row*512 + ks*64 + quad*16) ^ ((row & 7) << 4);
      bfr[ni] = *(const short8*)((const char*)preL + byte);
    }
    #pragma unroll
    for (int mi = 0; mi < 4; ++mi) {
      #pragma unroll
      for (int ni = 0; ni < 4; ++ni)
        acc[mi][ni] = __builtin_amdgcn_mfma_f32_16x16x32_f16(afr[mi], bfr[ni], acc[mi][ni], 0, 0, 0);
    }
  }
  #pragma unroll
  for (int mi = 0; mi < 4; ++mi) {
    #pragma unroll
    for (int r = 0; r < 4; ++r) {
      const int o = m0 + mi*16 + quad*4 + r;
      const float kb = biasL[o];
      #pragma unroll
      for (int ni = 0; ni < 4; ++ni) {
        float val = acc[mi][ni][r] + kb;
        val = val * sigm(val);   // SiLU
        out[((size_t)(b*256 + o))*16384 + pb*64 + ni*16 + lm] = val;
      }
    }
  }
}

extern "C" void kernel_launch(void* const* d_in, const int* in_sizes, int n_in,
                              void* d_out, int out_size, void* d_ws, size_t ws_size,
                              hipStream_t stream)
{
  (void)in_sizes; (void)n_in; (void)d_ws; (void)ws_size; (void)out_size;
  const float* x     = (const float*)d_in[0];
  const float* xyz   = (const float*)d_in[1];
  const float* Wproj = (const float*)d_in[4];
  const float* bproj = (const float*)d_in[5];
  const float* gnw   = (const float*)d_in[6];
  const float* gnb   = (const float*)d_in[7];
  const float* sa    = (const float*)d_in[8];
  const float* sb    = (const float*)d_in[9];
  float* out = (float*)d_out;

  hipLaunchKernelGGL(k0_geo,  dim3(16),   dim3(64),  0, stream, xyz);
  hipLaunchKernelGGL(k1a_cen, dim3(512),  dim3(128), 0, stream, x);
  hipLaunchKernelGGL(k1b_sim, dim3(2048), dim3(256), 0, stream, x, xyz, sa, sb);
  hipLaunchKernelGGL(k1c_red, dim3(128),  dim3(512), 0, stream);
  hipLaunchKernelGGL(k2_prep, dim3(4),    dim3(256), 0, stream, Wproj, bproj, gnw, gnb);
  hipLaunchKernelGGL(kf_proj, dim3(1024), dim3(256), 0, stream, out);
}

// Round 4
// 235.221 us; speedup vs baseline: 1.1058x; 1.1058x over previous
//
#include <hip/hip_runtime.h>
#include <stdint.h>

// B=4, DIM=256, W0=H0=128, HEADS=8, HEAD_DIM=32, FOLD=2, PROP=4
// 128 folded tiles (bb), each c=32, 64x64 (N=4096), M=16 centers.
// split_mask==0 => 7x7 conv contributes nothing; Wv/bv dead. All I/O f32.
// Pipeline: k01 geo+x centers | k1b MFMA sim+rowsum+dnum+Gram (5 blk/CU, no LDS atomics)
//           | k1c reduce + analytic GN stats | k2 GN-fold + W*alpha f16
//           | kf_proj: regenerate pre (sim.denss MFMA) in LDS + proj MFMA + SiLU
// Round-4: k1b LDS 40.9->29.8 KB (geo inline, xL overlay for per-wave partials),
// atomics/barrier removed; k0 merged into k1a. 5 launches.

typedef __attribute__((ext_vector_type(8))) short short8;
typedef __attribute__((ext_vector_type(4))) float floatx4;
typedef __fp16 fp16x2 __attribute__((ext_vector_type(2)));

#define SIMW 264     // padded half stride for [16][px] LDS tiles (528 B, 2-way banks)

__device__ float g_sbp[256];                           // per-tile GN partials [bb][2]
__device__ float g_bias[1024];
__device__ __attribute__((aligned(16))) _Float16 g_Wa[4*256*256];   // W*alpha, f16 [b][o][c]
__device__ float g_cenraw[128*16*32];
__device__ float g_cenhat[128*16*32];
__device__ float g_gcenhat[16*16*4];
__device__ __attribute__((aligned(16))) _Float16 g_sim[(size_t)128*4096*16];   // [tile][n][m]
__device__ float g_dnum[128*16*16*32];                 // [tile][chunk][m][c]
__device__ float g_Gp[(size_t)128*16*256];             // [tile][chunk][m][m'] Gram partials
__device__ float g_rsum[128*16*16];
__device__ __attribute__((aligned(16))) unsigned g_dnh2[128*256];   // denss f16 [tile][c][mpair]

static __device__ __forceinline__ fp16x2 as_h2(unsigned u) { return __builtin_bit_cast(fp16x2, u); }
static __device__ __forceinline__ unsigned pk(float a, float b) {
  return __builtin_bit_cast(unsigned, __builtin_amdgcn_cvt_pkrtz(a, b));
}
static __device__ __forceinline__ float h16(float v) {   // f32 -> f16(RTZ, matches pk) -> f32
  return (float)as_h2(pk(v, 0.f))[0];
}
#if __has_builtin(__builtin_amdgcn_fdot2)
static __device__ __forceinline__ float fdot2(fp16x2 a, fp16x2 b, float c) {
  return __builtin_amdgcn_fdot2(a, b, c, false);
}
#else
static __device__ __forceinline__ float fdot2(fp16x2 a, fp16x2 b, float c) {
  return c + (float)a[0]*(float)b[0] + (float)a[1]*(float)b[1];
}
#endif
static __device__ __forceinline__ float sum16(const float* p) {
  const float4* q = (const float4*)p;
  float4 a = q[0], b = q[1], c = q[2], d = q[3];
  return (a.x+a.y+a.z+a.w) + (b.x+b.y+b.z+b.w) + (c.x+c.y+c.z+c.w) + (d.x+d.y+d.z+d.w);
}
static __device__ __forceinline__ float sigm(float z) {
  return __builtin_amdgcn_rcpf(1.f + __expf(-z));
}

// ---------------- k01: x pooled centers (blk<512) + geo pooled centers (blk>=512) ----
__global__ __launch_bounds__(128) void k01_pool(const float* __restrict__ x,
                                                const float* __restrict__ xyz) {
  __shared__ float cenL[128];
  __shared__ float invL[4];
  __shared__ float gc[64];
  const int blk = blockIdx.x;
  const int tid = threadIdx.x;
  if (blk < 512) {
    const int bb = blk >> 2, pi = blk & 3;
    const int b = bb >> 5, e = (bb >> 2) & 7, f1 = (bb >> 1) & 1, f2 = bb & 1;
    const int c = tid >> 2, pj = tid & 3;
    const int m = pi*4 + pj;
    const float* p = x + ((size_t)(b*256 + e*32 + c)*128 + f1*64 + pi*16)*128 + f2*64 + pj*16;
    float s = 0.f;
    #pragma unroll
    for (int r = 0; r < 16; ++r) s += sum16(p + r*128);
    const float raw = s * (1.f/256.f);
    cenL[pj*32 + c] = raw;
    g_cenraw[(bb*16 + m)*32 + c] = raw;
    __syncthreads();
    if (tid < 4) {
      float ss = 0.f;
      #pragma unroll
      for (int cc = 0; cc < 32; ++cc) { float v = cenL[tid*32+cc]; ss += v*v; }
      invL[tid] = 1.f / fmaxf(sqrtf(ss), 1e-12f);
    }
    __syncthreads();
    g_cenhat[(bb*16 + m)*32 + c] = raw * invL[pj];
  } else {
    const int gti = blk - 512;
    const int bg = gti >> 2, f1 = (gti >> 1) & 1, f2 = gti & 1;
    if (tid < 48) {
      const int m = tid / 3, ch = tid - 3*(tid/3);
      const int pi = m >> 2, pj = m & 3;
      const float* p = xyz + (size_t)(bg*3+ch)*16384 + (f1*64 + pi*16)*128 + f2*64 + pj*16;
      float s = 0.f;
      #pragma unroll
      for (int r = 0; r < 16; ++r) s += sum16(p + r*128);
      gc[m*4+ch] = s * (1.f/256.f);
    }
    __syncthreads();
    if (tid < 16) {
      float g0 = gc[tid*4], g1 = gc[tid*4+1], g2 = gc[tid*4+2];
      float inv = 1.f / fmaxf(sqrtf(g0*g0+g1*g1+g2*g2), 1e-12f);
      float* o = g_gcenhat + gti*64 + tid*4;
      o[0] = g0*inv; o[1] = g1*inv; o[2] = g2*inv; o[3] = 0.f;
    }
  }
}

// ---------------- k1b: MFMA sim + rowsum + dnum + Gram partials ----------------
// 2048 blocks (tile x 16 chunks of 256 px), 256 threads = 4 waves.
// LDS 29.8 KB -> 5 blocks/CU. xL rows: 16 x-cpairs f16, invn, g0,g1,g2 (80 B).
// After phase 2, xL is dead and overlaid by per-wave partials wvD[4][512]+wvG[4][256].
__global__ __launch_bounds__(256, 5) void k1b_sim(const float* __restrict__ x,
                                                  const float* __restrict__ xyz,
                                                  const float* __restrict__ salpha,
                                                  const float* __restrict__ sbeta) {
  __shared__ __attribute__((aligned(16))) unsigned  xL[256*20];    // 20 KB
  __shared__ __attribute__((aligned(16))) _Float16 simS[16*SIMW];  // 8.25 KB
  __shared__ __attribute__((aligned(16))) unsigned chP[16*16];     // 1 KB
  __shared__ float gcenL[64];
  __shared__ float rsW[64];
  float* ovl = (float*)xL;             // phase-3 overlay: [0,2048) wvD, [2048,3072) wvG
  const int blk = blockIdx.x;
  const int bb = blk >> 4, ck = blk & 15;
  const int b = bb >> 5, e = (bb >> 2) & 7, f1 = (bb >> 1) & 1, f2 = bb & 1;
  const int gti = ((e & 3) << 2) | (f1 << 1) | f2;
  const int tid = threadIdx.x, lane = tid & 63, wave = tid >> 6;
  const int lm = lane & 15, quad = lane >> 4;
  const float alpha = salpha[0], beta = sbeta[0];
  const float* xt = x + (((size_t)(b*256 + e*32))*128 + f1*64)*128 + f2*64;

  {
    const float2 cp = *(const float2*)(g_cenhat + bb*512 + tid*2);
    chP[tid] = pk(cp.x, cp.y);
  }
  if (tid < 64) gcenL[tid] = g_gcenhat[gti*64 + tid];
  __syncthreads();

  // ---- phase 1: load own pixel, pack f16 -> xL, invn + normalized geo -> xL tail ----
  const int ng = ck*256 + tid;
  const int wi = ng >> 6, hi = ng & 63;
  const int addr = wi*128 + hi;
  {
    float ss = 0.f;
    unsigned xp[16];
    #pragma unroll
    for (int p = 0; p < 16; ++p) {
      const float v0 = xt[(size_t)(2*p)*16384 + addr];
      const float v1 = xt[(size_t)(2*p+1)*16384 + addr];
      ss += v0*v0 + v1*v1;
      xp[p] = pk(v0, v1);
    }
    uint4 u0 = {xp[0],xp[1],xp[2],xp[3]};
    uint4 u1 = {xp[4],xp[5],xp[6],xp[7]};
    uint4 u2 = {xp[8],xp[9],xp[10],xp[11]};
    uint4 u3 = {xp[12],xp[13],xp[14],xp[15]};
    *(uint4*)(xL + tid*20)      = u0;
    *(uint4*)(xL + tid*20 + 4)  = u1;
    *(uint4*)(xL + tid*20 + 8)  = u2;
    *(uint4*)(xL + tid*20 + 12) = u3;
    const float invn = __builtin_amdgcn_rcpf(fmaxf(sqrtf(ss), 1e-12f));
    const float* gp = xyz + (size_t)((e & 3)*3)*16384 + (f1*64 + wi)*128 + f2*64 + hi;
    float g0 = gp[0], g1 = gp[16384], g2 = gp[32768];
    const float invg = __builtin_amdgcn_rcpf(fmaxf(sqrtf(g0*g0+g1*g1+g2*g2), 1e-12f));
    float4 tail = {invn, g0*invg, g1*invg, g2*invg};
    *(float4*)((float*)xL + tid*20 + 16) = tail;
  }
  __syncthreads();

  // ---- phase 2: sim via MFMA (A=cen_hat[m][c], B=x_f16[px][c], K=32) + inline geo ----
  {
    const short8 afx = *(const short8*)((const _Float16*)chP + lm*32 + quad*8);
    float rsacc[4] = {0.f, 0.f, 0.f, 0.f};
    #pragma unroll
    for (int t = 0; t < 4; ++t) {
      const int px = wave*64 + t*16 + lm;
      const short8 bfx = *(const short8*)((const _Float16*)xL + px*40 + quad*8);
      floatx4 d = {0.f,0.f,0.f,0.f};
      d = __builtin_amdgcn_mfma_f32_16x16x32_f16(afx, bfx, d, 0, 0, 0);
      const float4 ig = *(const float4*)((const float*)xL + px*20 + 16);  // invn,g0,g1,g2
      #pragma unroll
      for (int r = 0; r < 4; ++r) {
        const int m = quad*4 + r;
        const float* gh = gcenL + m*4;
        const float dg = gh[0]*ig.y + gh[1]*ig.z + gh[2]*ig.w;
        const float gg = sigm(beta + alpha*dg);
        const float sv = sigm(beta + alpha * d[r] * ig.x) * gg * gg;
        rsacc[r] += sv;
        simS[m*SIMW + px] = (_Float16)sv;
      }
    }
    #pragma unroll
    for (int r = 0; r < 4; ++r) {
      float v = rsacc[r];
      v += __shfl_xor(v, 1, 64); v += __shfl_xor(v, 2, 64);
      v += __shfl_xor(v, 4, 64); v += __shfl_xor(v, 8, 64);
      if (lm == 0) rsW[wave*16 + quad*4 + r] = v;
    }
  }
  __syncthreads();   // xL dead from here; ovl live

  // ---- phase 3a: export sim f16 [px][m] to global ----
  {
    unsigned w[8];
    const unsigned short* sp = (const unsigned short*)simS;
    #pragma unroll
    for (int p = 0; p < 8; ++p)
      w[p] = (unsigned)sp[(2*p)*SIMW + tid] | ((unsigned)sp[(2*p+1)*SIMW + tid] << 16);
    _Float16* gp = g_sim + ((size_t)bb*4096 + ng)*16;
    *(uint4*)gp       = *(const uint4*)&w[0];
    *(uint4*)(gp + 8) = *(const uint4*)&w[4];
  }
  if (tid < 16)
    g_rsum[(bb*16 + ck)*16 + tid] = rsW[tid] + rsW[16+tid] + rsW[32+tid] + rsW[48+tid];

  // ---- phase 3b: dnum + Gram MFMAs -> per-wave partials in overlay (no atomics) ----
  {
    floatx4 acc0 = {0.f,0.f,0.f,0.f}, acc1 = {0.f,0.f,0.f,0.f};
    floatx4 accG = {0.f,0.f,0.f,0.f};
    #pragma unroll
    for (int ks = 0; ks < 2; ++ks) {
      const int kb = wave*64 + ks*32 + quad*8;                  // local px base
      const short8 af = *(const short8*)(simS + lm*SIMW + kb);  // A[m=lm][k=px]; also B[k][m'=lm]
      const int ag = ck*512 + ((kb >> 6)*128) + (kb & 63);
      const float* pb0 = xt + (size_t)lm*16384 + ag;            // B[c=lm][k=px]
      const float* pb1 = pb0 + (size_t)16*16384;                // c = lm+16
      short8 bf0, bf1;
      #pragma unroll
      for (int t = 0; t < 8; ++t) bf0[t] = __builtin_bit_cast(short, (_Float16)pb0[t]);
      #pragma unroll
      for (int t = 0; t < 8; ++t) bf1[t] = __builtin_bit_cast(short, (_Float16)pb1[t]);
      acc0 = __builtin_amdgcn_mfma_f32_16x16x32_f16(af, bf0, acc0, 0, 0, 0);
      acc1 = __builtin_amdgcn_mfma_f32_16x16x32_f16(af, bf1, acc1, 0, 0, 0);
      accG = __builtin_amdgcn_mfma_f32_16x16x32_f16(af, af,  accG, 0, 0, 0);
    }
    #pragma unroll
    for (int r = 0; r < 4; ++r) {
      const int m = quad*4 + r;
      ovl[wave*512 + m*32 + lm]        = acc0[r];
      ovl[wave*512 + m*32 + 16 + lm]   = acc1[r];
      ovl[2048 + wave*256 + m*16 + lm] = accG[r];
    }
  }
  __syncthreads();

  // ---- phase 3c: reduce 4 wave partials, store to global ----
  {
    const float d0 = ovl[tid]       + ovl[512 + tid]  + ovl[1024 + tid] + ovl[1536 + tid];
    const float d1 = ovl[256 + tid] + ovl[768 + tid]  + ovl[1280 + tid] + ovl[1792 + tid];
    g_dnum[(size_t)(bb*16 + ck)*512 + tid]       = d0;
    g_dnum[(size_t)(bb*16 + ck)*512 + 256 + tid] = d1;
    const float gsum = ovl[2048 + tid] + ovl[2304 + tid] + ovl[2560 + tid] + ovl[2816 + tid];
    g_Gp[(size_t)(bb*16 + ck)*256 + tid] = gsum;
  }
}

// ---------------- k1c: reduce partials -> denss f16 + analytic GN stats ----------------
__global__ __launch_bounds__(512) void k1c_red() {
  __shared__ float denssL[512];
  __shared__ float rsL[16];
  __shared__ float red[16];
  const int bb = blockIdx.x, tid = threadIdx.x, lane = tid & 63, wv = tid >> 6;
  if (tid < 16) {
    float r = 1.f;
    #pragma unroll
    for (int k = 0; k < 16; ++k) r += g_rsum[(bb*16 + k)*16 + tid];
    rsL[tid] = r;
  }
  float a = g_cenraw[bb*512 + tid];
  #pragma unroll
  for (int k = 0; k < 16; ++k) a += g_dnum[(size_t)bb*8192 + k*512 + tid];
  __syncthreads();
  denssL[tid] = a / rsL[tid >> 5];       // tid = m*32 + c
  __syncthreads();
  if (tid < 256) {
    const int c = tid >> 3, mp = tid & 7;
    g_dnh2[bb*256 + c*8 + mp] = pk(denssL[(2*mp)*32 + c], denssL[(2*mp+1)*32 + c]);
  }
  // ---- GN stats: s1 = sum_m rs[m]*sum_c d16; s2 = sum_{mm'} G[mm']*P[mm'] ----
  float contrib = 0.f;
  if (tid < 256) {
    const int m = tid >> 4, m2 = tid & 15;
    float g = 0.f;
    #pragma unroll
    for (int k = 0; k < 16; ++k) g += g_Gp[((size_t)bb*16 + k)*256 + tid];
    float p = 0.f;
    #pragma unroll
    for (int c = 0; c < 32; ++c)
      p += h16(denssL[m*32 + c]) * h16(denssL[m2*32 + c]);
    contrib = g * p;
  }
  float s1t = 0.f;
  if (tid < 16) {
    float sc = 0.f;
    #pragma unroll
    for (int c = 0; c < 32; ++c) sc += h16(denssL[tid*32 + c]);
    s1t = (rsL[tid] - 1.f) * sc;
  }
  #pragma unroll
  for (int off = 1; off < 64; off <<= 1) {
    contrib += __shfl_xor(contrib, off, 64);
    s1t     += __shfl_xor(s1t, off, 64);
  }
  if (lane == 0) { red[wv] = contrib; red[8 + wv] = s1t; }
  __syncthreads();
  if (tid == 0) {
    float s2 = 0.f, s1 = 0.f;
    #pragma unroll
    for (int w = 0; w < 8; ++w) { s2 += red[w]; s1 += red[8 + w]; }
    g_sbp[bb*2]     = s1;
    g_sbp[bb*2 + 1] = s2;
  }
}

// ---------------- k2: GN fold + bias + W*alpha (f16) ----------------
__global__ __launch_bounds__(256) void k2_prep(const float* __restrict__ Wp,
                                               const float* __restrict__ bpr,
                                               const float* __restrict__ gnw,
                                               const float* __restrict__ gnb) {
  __shared__ float betaL[256];
  __shared__ float alphaL[256];
  __shared__ float S12[2];
  const int b = blockIdx.x, t = threadIdx.x;
  if (t < 64) {
    float v1 = 0.f, v2 = 0.f;
    if (t < 32) { v1 = g_sbp[(b*32 + t)*2]; v2 = g_sbp[(b*32 + t)*2 + 1]; }
    #pragma unroll
    for (int off = 1; off < 64; off <<= 1) { v1 += __shfl_xor(v1, off, 64); v2 += __shfl_xor(v2, off, 64); }
    if (t == 0) { S12[0] = v1; S12[1] = v2; }
  }
  __syncthreads();
  const float S1 = S12[0];
  const float S2 = S12[1];
  const float inv_n = 1.f / 4194304.f;
  const float mu  = S1 * inv_n;
  const float inv = rsqrtf(fmaxf(S2*inv_n - mu*mu, 0.f) + 1e-5f);
  const float a = inv * gnw[t];
  alphaL[t] = a;
  betaL[t] = gnb[t] - mu * a;
  __syncthreads();
  float k = bpr[t];
  const float* wr = Wp + t*256;
  _Float16* wa = g_Wa + ((size_t)b*256 + t)*256;
  for (int c = 0; c < 256; c += 8) {
    const float4 w0 = *(const float4*)(wr + c);
    const float4 w1 = *(const float4*)(wr + c + 4);
    k += w0.x*betaL[c+0] + w0.y*betaL[c+1] + w0.z*betaL[c+2] + w0.w*betaL[c+3]
       + w1.x*betaL[c+4] + w1.y*betaL[c+5] + w1.z*betaL[c+6] + w1.w*betaL[c+7];
    uint4 o;
    o.x = pk(w0.x*alphaL[c+0], w0.y*alphaL[c+1]);
    o.y = pk(w0.z*alphaL[c+2], w0.w*alphaL[c+3]);
    o.z = pk(w1.x*alphaL[c+4], w1.y*alphaL[c+5]);
    o.w = pk(w1.z*alphaL[c+6], w1.w*alphaL[c+7]);
    *(uint4*)(wa + c) = o;
  }
  g_bias[b*256 + t] = k;
}

// ---------------- kf_proj: regenerate pre in LDS (sim.denss MFMA) + proj + SiLU --------
__global__ __launch_bounds__(256, 4) void kf_proj(float* __restrict__ out) {
  __shared__ __attribute__((aligned(16))) _Float16 preL[64*256];  // 32 KB, swizzled
  __shared__ float biasL[256];
  const int blk = blockIdx.x;
  const int b = blk >> 8, pb = blk & 255;
  const int f1 = pb >> 7, f2 = pb & 1;
  const int nbase = ((pb >> 1) & 63) * 64;
  const int tid = threadIdx.x, lane = tid & 63, wave = tid >> 6;
  const int lm = lane & 15, quad = lane >> 4;
  const int m0 = wave*64;
  biasL[tid] = g_bias[b*256 + tid];

  // ---- phase A: pre[px][c] = sum_m sim[px][m]*denss[m][c], K=16 (zero-padded to 32)
  #pragma unroll
  for (int eh = 0; eh < 2; ++eh) {
    const int e = wave*2 + eh;
    const int bb = b*32 + e*4 + f1*2 + f2;
    short8 bf0 = {}, bf1 = {};
    if (quad < 2) {                    // k = quad*8+t in [0,16): real m; quads 2,3 zero
      const _Float16* dp = (const _Float16*)g_dnh2 + (size_t)bb*512 + quad*8;
      bf0 = *(const short8*)(dp + lm*16);          // B[k=m][j=c=lm]
      bf1 = *(const short8*)(dp + (16 + lm)*16);   // c = 16+lm
    }
    #pragma unroll
    for (int pt = 0; pt < 4; ++pt) {
      const short8 af = *(const short8*)(g_sim
          + ((size_t)bb*4096 + nbase + pt*16 + lm)*16 + (quad & 1)*8);  // A[i=px=lm][k=m]
      floatx4 c0 = {0.f,0.f,0.f,0.f}, c1 = {0.f,0.f,0.f,0.f};
      c0 = __builtin_amdgcn_mfma_f32_16x16x32_f16(af, bf0, c0, 0, 0, 0);
      c1 = __builtin_amdgcn_mfma_f32_16x16x32_f16(af, bf1, c1, 0, 0, 0);
      #pragma unroll
      for (int r = 0; r < 4; ++r) {
        const int px = pt*16 + quad*4 + r;
        const int swz = (px & 7) << 4;
        const int b0 = (px*512 + (e*32 + lm)*2) ^ swz;
        const int b1 = (px*512 + (e*32 + 16 + lm)*2) ^ swz;
        *(_Float16*)((char*)preL + b0) = (_Float16)c0[r];
        *(_Float16*)((char*)preL + b1) = (_Float16)c1[r];
      }
    }
  }
  __syncthreads();

  // ---- phase B: proj MFMA + SiLU (B-frags from swizzled LDS) ----
  floatx4 acc[4][4] = {};
  #pragma unroll
  for (int ks = 0; ks < 8; ++ks) {
    const _Float16* abase = g_Wa + ((size_t)b*256)*256 + (size_t)ks*32 + quad*8;
    short8 afr[4], bfr[4];
    #pragma unroll
    for (int mi = 0; mi < 4; ++mi)
      afr[mi] = *(const short8*)(abase + (size_t)(m0 + mi*16 + lm)*256);
    #pragma unroll
    for (int ni = 0; ni < 4; ++ni) {
      const int row = ni*16 + lm;
      const int byte = (row*512 + ks*64 + quad*16) ^ ((row & 7) << 4);
      bfr[ni] = *(const short8*)((const char*)preL + byte);
    }
    #pragma unroll
    for (int mi = 0; mi < 4; ++mi) {
      #pragma unroll
      for (int ni = 0; ni < 4; ++ni)
        acc[mi][ni] = __builtin_amdgcn_mfma_f32_16x16x32_f16(afr[mi], bfr[ni], acc[mi][ni], 0, 0, 0);
    }
  }
  #pragma unroll
  for (int mi = 0; mi < 4; ++mi) {
    #pragma unroll
    for (int r = 0; r < 4; ++r) {
      const int o = m0 + mi*16 + quad*4 + r;
      const float kb = biasL[o];
      #pragma unroll
      for (int ni = 0; ni < 4; ++ni) {
        float val = acc[mi][ni][r] + kb;
        val = val * sigm(val);   // SiLU
        out[((size_t)(b*256 + o))*16384 + pb*64 + ni*16 + lm] = val;
      }
    }
  }
}

extern "C" void kernel_launch(void* const* d_in, const int* in_sizes, int n_in,
                              void* d_out, int out_size, void* d_ws, size_t ws_size,
                              hipStream_t stream)
{
  (void)in_sizes; (void)n_in; (void)d_ws; (void)ws_size; (void)out_size;
  const float* x     = (const float*)d_in[0];
  const float* xyz   = (const float*)d_in[1];
  const float* Wproj = (const float*)d_in[4];
  const float* bproj = (const float*)d_in[5];
  const float* gnw   = (const float*)d_in[6];
  const float* gnb   = (const float*)d_in[7];
  const float* sa    = (const float*)d_in[8];
  const float* sb    = (const float*)d_in[9];
  float* out = (float*)d_out;

  hipLaunchKernelGGL(k01_pool, dim3(528),  dim3(128), 0, stream, x, xyz);
  hipLaunchKernelGGL(k1b_sim,  dim3(2048), dim3(256), 0, stream, x, xyz, sa, sb);
  hipLaunchKernelGGL(k1c_red,  dim3(128),  dim3(512), 0, stream);
  hipLaunchKernelGGL(k2_prep,  dim3(4),    dim3(256), 0, stream, Wproj, bproj, gnw, gnb);
  hipLaunchKernelGGL(kf_proj,  dim3(1024), dim3(256), 0, stream, out);
}

// Round 6
// 222.847 us; speedup vs baseline: 1.1672x; 1.0555x over previous
//
#include <hip/hip_runtime.h>
#include <stdint.h>

// B=4, DIM=256, W0=H0=128, HEADS=8, HEAD_DIM=32, FOLD=2, PROP=4
// 128 folded tiles (bb), each c=32, 64x64 (N=4096), M=16 centers.
// split_mask==0 => 7x7 conv contributes nothing; Wv/bv dead. All I/O f32.
// Pipeline: k01 geo+x centers | k1b MFMA sim+rowsum+dnum+Gram (5 blk/CU, no LDS atomics)
//           | k1c reduce + analytic GN stats | k2 GN-fold + W*alpha f16
//           | kf_proj: regenerate pre (denss^T.sim^T MFMA) in LDS + proj MFMA + SiLU
// Round-5 (resubmit; round-5 bench was an infra failure, no kernel verdict):
// kf_proj phase A operand-swapped (C[i=c][j=px]) so each lane packs 4 consecutive c
// -> 16 conflict-free ds_write_b64 replace 64 4-way-conflicted ds_write_b16.

typedef __attribute__((ext_vector_type(8))) short short8;
typedef __attribute__((ext_vector_type(4))) float floatx4;
typedef __fp16 fp16x2 __attribute__((ext_vector_type(2)));

#define SIMW 264     // padded half stride for [16][px] LDS tiles (528 B, 2-way banks)

__device__ float g_sbp[256];                           // per-tile GN partials [bb][2]
__device__ float g_bias[1024];
__device__ __attribute__((aligned(16))) _Float16 g_Wa[4*256*256];   // W*alpha, f16 [b][o][c]
__device__ float g_cenraw[128*16*32];
__device__ float g_cenhat[128*16*32];
__device__ float g_gcenhat[16*16*4];
__device__ __attribute__((aligned(16))) _Float16 g_sim[(size_t)128*4096*16];   // [tile][n][m]
__device__ float g_dnum[128*16*16*32];                 // [tile][chunk][m][c]
__device__ float g_Gp[(size_t)128*16*256];             // [tile][chunk][m][m'] Gram partials
__device__ float g_rsum[128*16*16];
__device__ __attribute__((aligned(16))) unsigned g_dnh2[128*256];   // denss f16 [tile][c][mpair]

static __device__ __forceinline__ fp16x2 as_h2(unsigned u) { return __builtin_bit_cast(fp16x2, u); }
static __device__ __forceinline__ unsigned pk(float a, float b) {
  return __builtin_bit_cast(unsigned, __builtin_amdgcn_cvt_pkrtz(a, b));
}
static __device__ __forceinline__ float h16(float v) {   // f32 -> f16(RTZ, matches pk) -> f32
  return (float)as_h2(pk(v, 0.f))[0];
}
#if __has_builtin(__builtin_amdgcn_fdot2)
static __device__ __forceinline__ float fdot2(fp16x2 a, fp16x2 b, float c) {
  return __builtin_amdgcn_fdot2(a, b, c, false);
}
#else
static __device__ __forceinline__ float fdot2(fp16x2 a, fp16x2 b, float c) {
  return c + (float)a[0]*(float)b[0] + (float)a[1]*(float)b[1];
}
#endif
static __device__ __forceinline__ float sum16(const float* p) {
  const float4* q = (const float4*)p;
  float4 a = q[0], b = q[1], c = q[2], d = q[3];
  return (a.x+a.y+a.z+a.w) + (b.x+b.y+b.z+b.w) + (c.x+c.y+c.z+c.w) + (d.x+d.y+d.z+d.w);
}
static __device__ __forceinline__ float sigm(float z) {
  return __builtin_amdgcn_rcpf(1.f + __expf(-z));
}

// ---------------- k01: x pooled centers (blk<512) + geo pooled centers (blk>=512) ----
__global__ __launch_bounds__(128) void k01_pool(const float* __restrict__ x,
                                                const float* __restrict__ xyz) {
  __shared__ float cenL[128];
  __shared__ float invL[4];
  __shared__ float gc[64];
  const int blk = blockIdx.x;
  const int tid = threadIdx.x;
  if (blk < 512) {
    const int bb = blk >> 2, pi = blk & 3;
    const int b = bb >> 5, e = (bb >> 2) & 7, f1 = (bb >> 1) & 1, f2 = bb & 1;
    const int c = tid >> 2, pj = tid & 3;
    const int m = pi*4 + pj;
    const float* p = x + ((size_t)(b*256 + e*32 + c)*128 + f1*64 + pi*16)*128 + f2*64 + pj*16;
    float s = 0.f;
    #pragma unroll
    for (int r = 0; r < 16; ++r) s += sum16(p + r*128);
    const float raw = s * (1.f/256.f);
    cenL[pj*32 + c] = raw;
    g_cenraw[(bb*16 + m)*32 + c] = raw;
    __syncthreads();
    if (tid < 4) {
      float ss = 0.f;
      #pragma unroll
      for (int cc = 0; cc < 32; ++cc) { float v = cenL[tid*32+cc]; ss += v*v; }
      invL[tid] = 1.f / fmaxf(sqrtf(ss), 1e-12f);
    }
    __syncthreads();
    g_cenhat[(bb*16 + m)*32 + c] = raw * invL[pj];
  } else {
    const int gti = blk - 512;
    const int bg = gti >> 2, f1 = (gti >> 1) & 1, f2 = gti & 1;
    if (tid < 48) {
      const int m = tid / 3, ch = tid - 3*(tid/3);
      const int pi = m >> 2, pj = m & 3;
      const float* p = xyz + (size_t)(bg*3+ch)*16384 + (f1*64 + pi*16)*128 + f2*64 + pj*16;
      float s = 0.f;
      #pragma unroll
      for (int r = 0; r < 16; ++r) s += sum16(p + r*128);
      gc[m*4+ch] = s * (1.f/256.f);
    }
    __syncthreads();
    if (tid < 16) {
      float g0 = gc[tid*4], g1 = gc[tid*4+1], g2 = gc[tid*4+2];
      float inv = 1.f / fmaxf(sqrtf(g0*g0+g1*g1+g2*g2), 1e-12f);
      float* o = g_gcenhat + gti*64 + tid*4;
      o[0] = g0*inv; o[1] = g1*inv; o[2] = g2*inv; o[3] = 0.f;
    }
  }
}

// ---------------- k1b: MFMA sim + rowsum + dnum + Gram partials ----------------
// 2048 blocks (tile x 16 chunks of 256 px), 256 threads = 4 waves.
// LDS 29.8 KB -> 5 blocks/CU. xL rows: 16 x-cpairs f16, invn, g0,g1,g2 (80 B).
// After phase 2, xL is dead and overlaid by per-wave partials wvD[4][512]+wvG[4][256].
__global__ __launch_bounds__(256, 5) void k1b_sim(const float* __restrict__ x,
                                                  const float* __restrict__ xyz,
                                                  const float* __restrict__ salpha,
                                                  const float* __restrict__ sbeta) {
  __shared__ __attribute__((aligned(16))) unsigned  xL[256*20];    // 20 KB
  __shared__ __attribute__((aligned(16))) _Float16 simS[16*SIMW];  // 8.25 KB
  __shared__ __attribute__((aligned(16))) unsigned chP[16*16];     // 1 KB
  __shared__ float gcenL[64];
  __shared__ float rsW[64];
  float* ovl = (float*)xL;             // phase-3 overlay: [0,2048) wvD, [2048,3072) wvG
  const int blk = blockIdx.x;
  const int bb = blk >> 4, ck = blk & 15;
  const int b = bb >> 5, e = (bb >> 2) & 7, f1 = (bb >> 1) & 1, f2 = bb & 1;
  const int gti = ((e & 3) << 2) | (f1 << 1) | f2;
  const int tid = threadIdx.x, lane = tid & 63, wave = tid >> 6;
  const int lm = lane & 15, quad = lane >> 4;
  const float alpha = salpha[0], beta = sbeta[0];
  const float* xt = x + (((size_t)(b*256 + e*32))*128 + f1*64)*128 + f2*64;

  {
    const float2 cp = *(const float2*)(g_cenhat + bb*512 + tid*2);
    chP[tid] = pk(cp.x, cp.y);
  }
  if (tid < 64) gcenL[tid] = g_gcenhat[gti*64 + tid];
  __syncthreads();

  // ---- phase 1: load own pixel, pack f16 -> xL, invn + normalized geo -> xL tail ----
  const int ng = ck*256 + tid;
  const int wi = ng >> 6, hi = ng & 63;
  const int addr = wi*128 + hi;
  {
    float ss = 0.f;
    unsigned xp[16];
    #pragma unroll
    for (int p = 0; p < 16; ++p) {
      const float v0 = xt[(size_t)(2*p)*16384 + addr];
      const float v1 = xt[(size_t)(2*p+1)*16384 + addr];
      ss += v0*v0 + v1*v1;
      xp[p] = pk(v0, v1);
    }
    uint4 u0 = {xp[0],xp[1],xp[2],xp[3]};
    uint4 u1 = {xp[4],xp[5],xp[6],xp[7]};
    uint4 u2 = {xp[8],xp[9],xp[10],xp[11]};
    uint4 u3 = {xp[12],xp[13],xp[14],xp[15]};
    *(uint4*)(xL + tid*20)      = u0;
    *(uint4*)(xL + tid*20 + 4)  = u1;
    *(uint4*)(xL + tid*20 + 8)  = u2;
    *(uint4*)(xL + tid*20 + 12) = u3;
    const float invn = __builtin_amdgcn_rcpf(fmaxf(sqrtf(ss), 1e-12f));
    const float* gp = xyz + (size_t)((e & 3)*3)*16384 + (f1*64 + wi)*128 + f2*64 + hi;
    float g0 = gp[0], g1 = gp[16384], g2 = gp[32768];
    const float invg = __builtin_amdgcn_rcpf(fmaxf(sqrtf(g0*g0+g1*g1+g2*g2), 1e-12f));
    float4 tail = {invn, g0*invg, g1*invg, g2*invg};
    *(float4*)((float*)xL + tid*20 + 16) = tail;
  }
  __syncthreads();

  // ---- phase 2: sim via MFMA (A=cen_hat[m][c], B=x_f16[px][c], K=32) + inline geo ----
  {
    const short8 afx = *(const short8*)((const _Float16*)chP + lm*32 + quad*8);
    float rsacc[4] = {0.f, 0.f, 0.f, 0.f};
    #pragma unroll
    for (int t = 0; t < 4; ++t) {
      const int px = wave*64 + t*16 + lm;
      const short8 bfx = *(const short8*)((const _Float16*)xL + px*40 + quad*8);
      floatx4 d = {0.f,0.f,0.f,0.f};
      d = __builtin_amdgcn_mfma_f32_16x16x32_f16(afx, bfx, d, 0, 0, 0);
      const float4 ig = *(const float4*)((const float*)xL + px*20 + 16);  // invn,g0,g1,g2
      #pragma unroll
      for (int r = 0; r < 4; ++r) {
        const int m = quad*4 + r;
        const float* gh = gcenL + m*4;
        const float dg = gh[0]*ig.y + gh[1]*ig.z + gh[2]*ig.w;
        const float gg = sigm(beta + alpha*dg);
        const float sv = sigm(beta + alpha * d[r] * ig.x) * gg * gg;
        rsacc[r] += sv;
        simS[m*SIMW + px] = (_Float16)sv;
      }
    }
    #pragma unroll
    for (int r = 0; r < 4; ++r) {
      float v = rsacc[r];
      v += __shfl_xor(v, 1, 64); v += __shfl_xor(v, 2, 64);
      v += __shfl_xor(v, 4, 64); v += __shfl_xor(v, 8, 64);
      if (lm == 0) rsW[wave*16 + quad*4 + r] = v;
    }
  }
  __syncthreads();   // xL dead from here; ovl live

  // ---- phase 3a: export sim f16 [px][m] to global ----
  {
    unsigned w[8];
    const unsigned short* sp = (const unsigned short*)simS;
    #pragma unroll
    for (int p = 0; p < 8; ++p)
      w[p] = (unsigned)sp[(2*p)*SIMW + tid] | ((unsigned)sp[(2*p+1)*SIMW + tid] << 16);
    _Float16* gp = g_sim + ((size_t)bb*4096 + ng)*16;
    *(uint4*)gp       = *(const uint4*)&w[0];
    *(uint4*)(gp + 8) = *(const uint4*)&w[4];
  }
  if (tid < 16)
    g_rsum[(bb*16 + ck)*16 + tid] = rsW[tid] + rsW[16+tid] + rsW[32+tid] + rsW[48+tid];

  // ---- phase 3b: dnum + Gram MFMAs -> per-wave partials in overlay (no atomics) ----
  {
    floatx4 acc0 = {0.f,0.f,0.f,0.f}, acc1 = {0.f,0.f,0.f,0.f};
    floatx4 accG = {0.f,0.f,0.f,0.f};
    #pragma unroll
    for (int ks = 0; ks < 2; ++ks) {
      const int kb = wave*64 + ks*32 + quad*8;                  // local px base
      const short8 af = *(const short8*)(simS + lm*SIMW + kb);  // A[m=lm][k=px]; also B[k][m'=lm]
      const int ag = ck*512 + ((kb >> 6)*128) + (kb & 63);
      const float* pb0 = xt + (size_t)lm*16384 + ag;            // B[c=lm][k=px]
      const float* pb1 = pb0 + (size_t)16*16384;                // c = lm+16
      short8 bf0, bf1;
      #pragma unroll
      for (int t = 0; t < 8; ++t) bf0[t] = __builtin_bit_cast(short, (_Float16)pb0[t]);
      #pragma unroll
      for (int t = 0; t < 8; ++t) bf1[t] = __builtin_bit_cast(short, (_Float16)pb1[t]);
      acc0 = __builtin_amdgcn_mfma_f32_16x16x32_f16(af, bf0, acc0, 0, 0, 0);
      acc1 = __builtin_amdgcn_mfma_f32_16x16x32_f16(af, bf1, acc1, 0, 0, 0);
      accG = __builtin_amdgcn_mfma_f32_16x16x32_f16(af, af,  accG, 0, 0, 0);
    }
    #pragma unroll
    for (int r = 0; r < 4; ++r) {
      const int m = quad*4 + r;
      ovl[wave*512 + m*32 + lm]        = acc0[r];
      ovl[wave*512 + m*32 + 16 + lm]   = acc1[r];
      ovl[2048 + wave*256 + m*16 + lm] = accG[r];
    }
  }
  __syncthreads();

  // ---- phase 3c: reduce 4 wave partials, store to global ----
  {
    const float d0 = ovl[tid]       + ovl[512 + tid]  + ovl[1024 + tid] + ovl[1536 + tid];
    const float d1 = ovl[256 + tid] + ovl[768 + tid]  + ovl[1280 + tid] + ovl[1792 + tid];
    g_dnum[(size_t)(bb*16 + ck)*512 + tid]       = d0;
    g_dnum[(size_t)(bb*16 + ck)*512 + 256 + tid] = d1;
    const float gsum = ovl[2048 + tid] + ovl[2304 + tid] + ovl[2560 + tid] + ovl[2816 + tid];
    g_Gp[(size_t)(bb*16 + ck)*256 + tid] = gsum;
  }
}

// ---------------- k1c: reduce partials -> denss f16 + analytic GN stats ----------------
__global__ __launch_bounds__(512) void k1c_red() {
  __shared__ float denssL[512];
  __shared__ float rsL[16];
  __shared__ float red[16];
  const int bb = blockIdx.x, tid = threadIdx.x, lane = tid & 63, wv = tid >> 6;
  if (tid < 16) {
    float r = 1.f;
    #pragma unroll
    for (int k = 0; k < 16; ++k) r += g_rsum[(bb*16 + k)*16 + tid];
    rsL[tid] = r;
  }
  float a = g_cenraw[bb*512 + tid];
  #pragma unroll
  for (int k = 0; k < 16; ++k) a += g_dnum[(size_t)bb*8192 + k*512 + tid];
  __syncthreads();
  denssL[tid] = a / rsL[tid >> 5];       // tid = m*32 + c
  __syncthreads();
  if (tid < 256) {
    const int c = tid >> 3, mp = tid & 7;
    g_dnh2[bb*256 + c*8 + mp] = pk(denssL[(2*mp)*32 + c], denssL[(2*mp+1)*32 + c]);
  }
  // ---- GN stats: s1 = sum_m rs[m]*sum_c d16; s2 = sum_{mm'} G[mm']*P[mm'] ----
  float contrib = 0.f;
  if (tid < 256) {
    const int m = tid >> 4, m2 = tid & 15;
    float g = 0.f;
    #pragma unroll
    for (int k = 0; k < 16; ++k) g += g_Gp[((size_t)bb*16 + k)*256 + tid];
    float p = 0.f;
    #pragma unroll
    for (int c = 0; c < 32; ++c)
      p += h16(denssL[m*32 + c]) * h16(denssL[m2*32 + c]);
    contrib = g * p;
  }
  float s1t = 0.f;
  if (tid < 16) {
    float sc = 0.f;
    #pragma unroll
    for (int c = 0; c < 32; ++c) sc += h16(denssL[tid*32 + c]);
    s1t = (rsL[tid] - 1.f) * sc;
  }
  #pragma unroll
  for (int off = 1; off < 64; off <<= 1) {
    contrib += __shfl_xor(contrib, off, 64);
    s1t     += __shfl_xor(s1t, off, 64);
  }
  if (lane == 0) { red[wv] = contrib; red[8 + wv] = s1t; }
  __syncthreads();
  if (tid == 0) {
    float s2 = 0.f, s1 = 0.f;
    #pragma unroll
    for (int w = 0; w < 8; ++w) { s2 += red[w]; s1 += red[8 + w]; }
    g_sbp[bb*2]     = s1;
    g_sbp[bb*2 + 1] = s2;
  }
}

// ---------------- k2: GN fold + bias + W*alpha (f16) ----------------
__global__ __launch_bounds__(256) void k2_prep(const float* __restrict__ Wp,
                                               const float* __restrict__ bpr,
                                               const float* __restrict__ gnw,
                                               const float* __restrict__ gnb) {
  __shared__ float betaL[256];
  __shared__ float alphaL[256];
  __shared__ float S12[2];
  const int b = blockIdx.x, t = threadIdx.x;
  if (t < 64) {
    float v1 = 0.f, v2 = 0.f;
    if (t < 32) { v1 = g_sbp[(b*32 + t)*2]; v2 = g_sbp[(b*32 + t)*2 + 1]; }
    #pragma unroll
    for (int off = 1; off < 64; off <<= 1) { v1 += __shfl_xor(v1, off, 64); v2 += __shfl_xor(v2, off, 64); }
    if (t == 0) { S12[0] = v1; S12[1] = v2; }
  }
  __syncthreads();
  const float S1 = S12[0];
  const float S2 = S12[1];
  const float inv_n = 1.f / 4194304.f;
  const float mu  = S1 * inv_n;
  const float inv = rsqrtf(fmaxf(S2*inv_n - mu*mu, 0.f) + 1e-5f);
  const float a = inv * gnw[t];
  alphaL[t] = a;
  betaL[t] = gnb[t] - mu * a;
  __syncthreads();
  float k = bpr[t];
  const float* wr = Wp + t*256;
  _Float16* wa = g_Wa + ((size_t)b*256 + t)*256;
  for (int c = 0; c < 256; c += 8) {
    const float4 w0 = *(const float4*)(wr + c);
    const float4 w1 = *(const float4*)(wr + c + 4);
    k += w0.x*betaL[c+0] + w0.y*betaL[c+1] + w0.z*betaL[c+2] + w0.w*betaL[c+3]
       + w1.x*betaL[c+4] + w1.y*betaL[c+5] + w1.z*betaL[c+6] + w1.w*betaL[c+7];
    uint4 o;
    o.x = pk(w0.x*alphaL[c+0], w0.y*alphaL[c+1]);
    o.y = pk(w0.z*alphaL[c+2], w0.w*alphaL[c+3]);
    o.z = pk(w1.x*alphaL[c+4], w1.y*alphaL[c+5]);
    o.w = pk(w1.z*alphaL[c+6], w1.w*alphaL[c+7]);
    *(uint4*)(wa + c) = o;
  }
  g_bias[b*256 + t] = k;
}

// ---------------- kf_proj: regenerate pre in LDS (denss^T.sim^T MFMA) + proj + SiLU ----
// Phase A (swapped operands): C[i=c][j=px]; lane (lm,quad) holds 4 consecutive c
// (quad*4+r) at px=lm -> one 8B ds_write_b64 per c-half, conflict-free after swizzle.
// Phase B unchanged: proj MFMA with B-frags from swizzled LDS.
__global__ __launch_bounds__(256, 4) void kf_proj(float* __restrict__ out) {
  __shared__ __attribute__((aligned(16))) _Float16 preL[64*256];  // 32 KB, swizzled
  __shared__ float biasL[256];
  const int blk = blockIdx.x;
  const int b = blk >> 8, pb = blk & 255;
  const int f1 = pb >> 7, f2 = pb & 1;
  const int nbase = ((pb >> 1) & 63) * 64;
  const int tid = threadIdx.x, lane = tid & 63, wave = tid >> 6;
  const int lm = lane & 15, quad = lane >> 4;
  const int m0 = wave*64;
  biasL[tid] = g_bias[b*256 + tid];

  // ---- phase A: pre[px][c] = sum_m sim[px][m]*denss[m][c]; A=denss[c][m], B=sim^T[m][px]
  #pragma unroll
  for (int eh = 0; eh < 2; ++eh) {
    const int e = wave*2 + eh;
    const int bb = b*32 + e*4 + f1*2 + f2;
    short8 af0 = {}, af1 = {};
    if (quad < 2) {                    // k = quad*8+t in [0,16): real m; quads 2,3 zero
      const _Float16* dp = (const _Float16*)(g_dnh2 + (size_t)bb*256) + quad*8;
      af0 = *(const short8*)(dp + lm*16);          // A[i=c=lm][k=m]
      af1 = *(const short8*)(dp + (16 + lm)*16);   // c = 16+lm
    }
    #pragma unroll
    for (int pt = 0; pt < 4; ++pt) {
      short8 bf = {};
      if (quad < 2)
        bf = *(const short8*)(g_sim
            + ((size_t)bb*4096 + nbase + pt*16 + lm)*16 + quad*8);  // B[k=m][j=px=lm]
      floatx4 c0 = {0.f,0.f,0.f,0.f}, c1 = {0.f,0.f,0.f,0.f};
      c0 = __builtin_amdgcn_mfma_f32_16x16x32_f16(af0, bf, c0, 0, 0, 0);
      c1 = __builtin_amdgcn_mfma_f32_16x16x32_f16(af1, bf, c1, 0, 0, 0);
      const int px = pt*16 + lm;
      const int swz = (px & 7) << 4;
      const int b0 = (px*512 + (e*32 + quad*4)*2) ^ swz;
      const int b1 = (px*512 + (e*32 + 16 + quad*4)*2) ^ swz;
      uint2 w0; w0.x = pk(c0[0], c0[1]); w0.y = pk(c0[2], c0[3]);
      uint2 w1; w1.x = pk(c1[0], c1[1]); w1.y = pk(c1[2], c1[3]);
      *(uint2*)((char*)preL + b0) = w0;
      *(uint2*)((char*)preL + b1) = w1;
    }
  }
  __syncthreads();

  // ---- phase B: proj MFMA + SiLU (B-frags from swizzled LDS) ----
  floatx4 acc[4][4] = {};
  #pragma unroll
  for (int ks = 0; ks < 8; ++ks) {
    const _Float16* abase = g_Wa + ((size_t)b*256)*256 + (size_t)ks*32 + quad*8;
    short8 afr[4], bfr[4];
    #pragma unroll
    for (int mi = 0; mi < 4; ++mi)
      afr[mi] = *(const short8*)(abase + (size_t)(m0 + mi*16 + lm)*256);
    #pragma unroll
    for (int ni = 0; ni < 4; ++ni) {
      const int row = ni*16 + lm;
      const int byte = (row*512 + ks*64 + quad*16) ^ ((row & 7) << 4);
      bfr[ni] = *(const short8*)((const char*)preL + byte);
    }
    #pragma unroll
    for (int mi = 0; mi < 4; ++mi) {
      #pragma unroll
      for (int ni = 0; ni < 4; ++ni)
        acc[mi][ni] = __builtin_amdgcn_mfma_f32_16x16x32_f16(afr[mi], bfr[ni], acc[mi][ni], 0, 0, 0);
    }
  }
  #pragma unroll
  for (int mi = 0; mi < 4; ++mi) {
    #pragma unroll
    for (int r = 0; r < 4; ++r) {
      const int o = m0 + mi*16 + quad*4 + r;
      const float kb = biasL[o];
      #pragma unroll
      for (int ni = 0; ni < 4; ++ni) {
        float val = acc[mi][ni][r] + kb;
        val = val * sigm(val);   // SiLU
        out[((size_t)(b*256 + o))*16384 + pb*64 + ni*16 + lm] = val;
      }
    }
  }
}

extern "C" void kernel_launch(void* const* d_in, const int* in_sizes, int n_in,
                              void* d_out, int out_size, void* d_ws, size_t ws_size,
                              hipStream_t stream)
{
  (void)in_sizes; (void)n_in; (void)d_ws; (void)ws_size; (void)out_size;
  const float* x     = (const float*)d_in[0];
  const float* xyz   = (const float*)d_in[1];
  const float* Wproj = (const float*)d_in[4];
  const float* bproj = (const float*)d_in[5];
  const float* gnw   = (const float*)d_in[6];
  const float* gnb   = (const float*)d_in[7];
  const float* sa    = (const float*)d_in[8];
  const float* sb    = (const float*)d_in[9];
  float* out = (float*)d_out;

  hipLaunchKernelGGL(k01_pool, dim3(528),  dim3(128), 0, stream, x, xyz);
  hipLaunchKernelGGL(k1b_sim,  dim3(2048), dim3(256), 0, stream, x, xyz, sa, sb);
  hipLaunchKernelGGL(k1c_red,  dim3(128),  dim3(512), 0, stream);
  hipLaunchKernelGGL(k2_prep,  dim3(4),    dim3(256), 0, stream, Wproj, bproj, gnw, gnb);
  hipLaunchKernelGGL(kf_proj,  dim3(1024), dim3(256), 0, stream, out);
}